// Round 1
// baseline (3190.284 us; speedup 1.0000x reference)
//
#include <hip/hip_runtime.h>
#include <hip/hip_bf16.h>

#define B_ 16
#define S_ 2048
#define H_ 1024
#define U_ 512
#define NH 8
#define TOPK 100

#define M_ (B_*S_)      // 32768 rows (b,s)
#define NC (NH*U_)      // 4096 cols (n,u)
#define ROWT 128
#define COLT 128
#define BK 16
#define NROWT (M_/ROWT)  // 256
#define NCOLT (NC/COLT)  // 32

__device__ __forceinline__ float fast_tanh(float x) {
    // tanh(x) = (e^{2x}-1)/(e^{2x}+1); |x| <~ 8 here, no overflow risk
    float e = __expf(2.f * x);
    return (e - 1.f) / (e + 1.f);
}

// qb[n,b,u] = sum_h query[b,h]*W2[n,h,u] + b1[n,u] + b2[n,u]
__global__ void qb_kernel(const float* __restrict__ query,
                          const float* __restrict__ W2,
                          const float* __restrict__ b1,
                          const float* __restrict__ b2,
                          float* __restrict__ qb) {
    int n = blockIdx.x >> 4;
    int b = blockIdx.x & 15;
    __shared__ float q[H_];
    int tid = threadIdx.x; // 0..511
    q[tid]       = query[b * H_ + tid];
    q[tid + 512] = query[b * H_ + tid + 512];
    __syncthreads();
    const float* w2 = W2 + (size_t)n * H_ * U_ + tid;
    float acc = 0.f;
    #pragma unroll 4
    for (int h = 0; h < H_; ++h) acc += q[h] * w2[(size_t)h * U_];
    acc += b1[n * U_ + tid] + b2[n * U_ + tid];
    qb[(n * B_ + b) * U_ + tid] = acc;
}

// Fused GEMM + tanh*Vw epilogue. Output: partial[colTile][row] (deterministic,
// summed in fixed order later). Tile 128x128, K-chunk 16, 8x8 per thread.
__global__ __launch_bounds__(256, 2) void gemm_score(
        const float* __restrict__ values,
        const float* __restrict__ W1,
        const float* __restrict__ qb,
        const float* __restrict__ Vw,
        const float* __restrict__ Ww,
        float* __restrict__ partial) {
    __shared__ float As[BK][ROWT + 4]; // transposed: As[k][row]
    __shared__ float Bs[BK][COLT + 4];
    int tid = threadIdx.x;
    int tx = tid & 15, ty = tid >> 4;
    int rowBase = blockIdx.x * ROWT;
    int colBase = blockIdx.y * COLT;
    int n  = colBase >> 9;   // head (tiles never straddle heads: 512/128=4)
    int u0 = colBase & 511;
    int b  = rowBase >> 11;  // batch (tiles never straddle batches)

    float acc[8][8];
    #pragma unroll
    for (int i = 0; i < 8; ++i)
        #pragma unroll
        for (int j = 0; j < 8; ++j) acc[i][j] = 0.f;

    const float* Ag = values + (size_t)rowBase * H_;
    const float* Bg = W1 + (size_t)n * H_ * U_ + u0;

    for (int k0 = 0; k0 < H_; k0 += BK) {
        #pragma unroll
        for (int r = 0; r < 2; ++r) {
            int idx = tid + r * 256;
            int arow = idx >> 2, aqc = idx & 3;
            float4 v = *(const float4*)(Ag + (size_t)arow * H_ + k0 + aqc * 4);
            As[aqc * 4 + 0][arow] = v.x;
            As[aqc * 4 + 1][arow] = v.y;
            As[aqc * 4 + 2][arow] = v.z;
            As[aqc * 4 + 3][arow] = v.w;
        }
        #pragma unroll
        for (int r = 0; r < 2; ++r) {
            int idx = tid + r * 256;
            int bk = idx >> 5, bqc = idx & 31;
            float4 v = *(const float4*)(Bg + (size_t)(k0 + bk) * U_ + bqc * 4);
            *(float4*)&Bs[bk][bqc * 4] = v;
        }
        __syncthreads();
        #pragma unroll
        for (int k = 0; k < BK; ++k) {
            float4 a0 = *(const float4*)&As[k][ty * 8];
            float4 a1 = *(const float4*)&As[k][ty * 8 + 4];
            float4 b0 = *(const float4*)&Bs[k][tx * 8];
            float4 b1v = *(const float4*)&Bs[k][tx * 8 + 4];
            float av[8] = {a0.x, a0.y, a0.z, a0.w, a1.x, a1.y, a1.z, a1.w};
            float bv[8] = {b0.x, b0.y, b0.z, b0.w, b1v.x, b1v.y, b1v.z, b1v.w};
            #pragma unroll
            for (int i = 0; i < 8; ++i)
                #pragma unroll
                for (int j = 0; j < 8; ++j)
                    acc[i][j] = fmaf(av[i], bv[j], acc[i][j]);
        }
        __syncthreads();
    }

    // epilogue: p_row = sum_u Vw[n,u]*tanh(acc + qb[n,b,u]); scale by Ww[n]
    float qbv[8], vwv[8];
    #pragma unroll
    for (int j = 0; j < 8; ++j) {
        int u = u0 + tx * 8 + j;
        qbv[j] = qb[(n * B_ + b) * U_ + u];
        vwv[j] = Vw[n * U_ + u];
    }
    float wwn = Ww[n];
    #pragma unroll
    for (int i = 0; i < 8; ++i) {
        float p = 0.f;
        #pragma unroll
        for (int j = 0; j < 8; ++j)
            p += vwv[j] * fast_tanh(acc[i][j] + qbv[j]);
        p += __shfl_xor(p, 1);
        p += __shfl_xor(p, 2);
        p += __shfl_xor(p, 4);
        p += __shfl_xor(p, 8);
        if (tx == 0)
            partial[(size_t)blockIdx.y * M_ + rowBase + ty * 8 + i] = wwn * p;
    }
}

__global__ void reduce_score(const float* __restrict__ partial,
                             float* __restrict__ score) {
    int row = blockIdx.x * blockDim.x + threadIdx.x;
    float s = 0.f;
    #pragma unroll
    for (int ct = 0; ct < NCOLT; ++ct) s += partial[(size_t)ct * M_ + row];
    score[row] = s;
}

// Per-batch top-K: bitonic sort row in LDS, threshold = 100th largest,
// ties at T resolved by lowest index (jax top_k semantics).
__global__ __launch_bounds__(1024) void topk_kernel(
        const float* __restrict__ score,
        const float* __restrict__ Vb,
        const float* __restrict__ Ww,
        const float* __restrict__ Wb,
        float* __restrict__ out_masked,
        float* __restrict__ w_un) {
    __shared__ float sc[S_];
    __shared__ float srt[S_];
    __shared__ int cnt_gt;
    int b = blockIdx.x;
    int tid = threadIdx.x;
    float cst = Wb[0];
    #pragma unroll
    for (int n2 = 0; n2 < NH; ++n2) cst += Ww[n2] * Vb[n2];
    for (int s = tid; s < S_; s += 1024) {
        float v = score[b * S_ + s] + cst;
        sc[s] = v; srt[s] = v;
    }
    if (tid == 0) cnt_gt = 0;
    __syncthreads();
    // ascending bitonic sort of srt[0..2047], 1024 threads = 1 pair each
    for (int k = 2; k <= S_; k <<= 1) {
        for (int j = k >> 1; j >= 1; j >>= 1) {
            int i = ((tid & ~(j - 1)) << 1) | (tid & (j - 1));
            int p = i | j;
            float a = srt[i], c2 = srt[p];
            if (((i & k) == 0) ? (a > c2) : (a < c2)) { srt[i] = c2; srt[p] = a; }
            __syncthreads();
        }
    }
    float T = srt[S_ - TOPK]; // 100th largest
    int c = 0;
    for (int s = tid; s < S_; s += 1024) c += (sc[s] > T);
    atomicAdd(&cnt_gt, c);
    __syncthreads();
    int need_eq = TOPK - cnt_gt;
    for (int s = tid; s < S_; s += 1024) {
        float v = sc[s];
        bool sel = (v > T);
        if (v == T) {
            int rank = 0;
            for (int t2 = 0; t2 < s; ++t2) rank += (sc[t2] == T);
            sel = (rank < need_eq);
        }
        float m = sel ? v : 0.f;
        out_masked[b * S_ + s] = m;
        w_un[b * S_ + s] = 1.f / (1.f + __expf(-m));
    }
}

// denom over batch dim, then normalized w
__global__ void norm_w(const float* __restrict__ w_un, float* __restrict__ out_w) {
    int s = blockIdx.x * blockDim.x + threadIdx.x; // 2048 total
    float d = 0.f;
    #pragma unroll
    for (int b = 0; b < B_; ++b) d += w_un[b * S_ + s];
    float inv = 1.f / d;
    #pragma unroll
    for (int b = 0; b < B_; ++b) out_w[b * S_ + s] = w_un[b * S_ + s] * inv;
}

// context partials over s-chunks (deterministic reduce after)
__global__ void ctx_partial(const float* __restrict__ values,
                            const float* __restrict__ w,
                            float* __restrict__ pctx) {
    int bb = blockIdx.x;
    int h = blockIdx.y * 256 + threadIdx.x;
    int s0 = blockIdx.z * 256;
    __shared__ float wrow[256];
    wrow[threadIdx.x] = w[bb * S_ + s0 + threadIdx.x];
    __syncthreads();
    const float* vp = values + (size_t)(bb * S_ + s0) * H_ + h;
    float acc = 0.f;
    #pragma unroll 4
    for (int s = 0; s < 256; ++s) acc += wrow[s] * vp[(size_t)s * H_];
    pctx[((size_t)blockIdx.z * B_ + bb) * H_ + h] = acc;
}

__global__ void ctx_reduce(const float* __restrict__ pctx,
                           float* __restrict__ out_ctx) {
    int i = blockIdx.x * blockDim.x + threadIdx.x; // 16384
    float s = 0.f;
    #pragma unroll
    for (int z = 0; z < 8; ++z) s += pctx[(size_t)z * B_ * H_ + i];
    out_ctx[i] = s;
}

extern "C" void kernel_launch(void* const* d_in, const int* in_sizes, int n_in,
                              void* d_out, int out_size, void* d_ws, size_t ws_size,
                              hipStream_t stream) {
    const float* query = (const float*)d_in[0];
    const float* values = (const float*)d_in[1];
    const float* W1 = (const float*)d_in[2];
    const float* b1 = (const float*)d_in[3];
    const float* W2 = (const float*)d_in[4];
    const float* b2 = (const float*)d_in[5];
    const float* Vw = (const float*)d_in[6];
    const float* Vb = (const float*)d_in[7];
    const float* Ww = (const float*)d_in[8];
    const float* Wb = (const float*)d_in[9];

    float* ws = (float*)d_ws;
    float* qb      = ws;                     // 65536
    float* partial = qb + 65536;             // 32*32768 = 1048576
    float* score   = partial + 1048576;      // 32768
    float* w_un    = score + 32768;          // 32768
    float* pctx    = w_un + 32768;           // 8*16*1024 = 131072
    // total ws: 5.25 MB

    float* out_ctx    = (float*)d_out;       // 16384
    float* out_w      = out_ctx + 16384;     // 32768
    float* out_masked = out_w + 32768;       // 32768

    qb_kernel<<<dim3(NH * B_), 512, 0, stream>>>(query, W2, b1, b2, qb);
    gemm_score<<<dim3(NROWT, NCOLT), 256, 0, stream>>>(values, W1, qb, Vw, Ww, partial);
    reduce_score<<<128, 256, 0, stream>>>(partial, score);
    topk_kernel<<<16, 1024, 0, stream>>>(score, Vb, Ww, Wb, out_masked, w_un);
    norm_w<<<8, 256, 0, stream>>>(w_un, out_w);
    ctx_partial<<<dim3(16, 4, 8), 256, 0, stream>>>(values, out_w, pctx);
    ctx_reduce<<<64, 256, 0, stream>>>(pctx, out_ctx);
}

// Round 2
// 1161.128 us; speedup vs baseline: 2.7476x; 2.7476x over previous
//
#include <hip/hip_runtime.h>
#include <hip/hip_bf16.h>

#define B_ 16
#define S_ 2048
#define H_ 1024
#define U_ 512
#define NH 8
#define TOPK 100

#define M_ (B_*S_)      // 32768 rows (b,s)
#define NC (NH*U_)      // 4096 cols (n,u)
#define NCOLT 32        // 4096/128 column tiles

typedef short s16x8 __attribute__((ext_vector_type(8)));
typedef float f32x4 __attribute__((ext_vector_type(4)));

__device__ __forceinline__ float fast_tanh(float x) {
    float e = __expf(2.f * x);
    return (e - 1.f) / (e + 1.f);
}

// round-to-nearest-even fp32 -> bf16 (no NaN inputs here)
__device__ __forceinline__ unsigned short f2bf(float f) {
    unsigned u = __float_as_uint(f);
    u = u + 0x7fffu + ((u >> 16) & 1u);
    return (unsigned short)(u >> 16);
}

__device__ __forceinline__ void gload_lds16(const void* g, void* l) {
    __builtin_amdgcn_global_load_lds(
        (const __attribute__((address_space(1))) void*)g,
        (__attribute__((address_space(3))) void*)l, 16, 0, 0);
}

// ---------------- prep: fp32 -> bf16 hi/lo ----------------

// values [M,H] -> Ahi, Alo bf16 [M,H]
__global__ void convert_A(const float* __restrict__ v,
                          unsigned short* __restrict__ hi,
                          unsigned short* __restrict__ lo) {
    size_t i = ((size_t)blockIdx.x * 256 + threadIdx.x) * 4;
    float4 f = *(const float4*)(v + i);
    float c[4] = {f.x, f.y, f.z, f.w};
    unsigned short hh[4], ll[4];
    #pragma unroll
    for (int j = 0; j < 4; ++j) {
        unsigned short h = f2bf(c[j]);
        float hf = __uint_as_float((unsigned)h << 16);
        hh[j] = h;
        ll[j] = f2bf(c[j] - hf);   // hi/lo split: |err| <= 2^-17 |x|
    }
    *(ushort4*)(hi + i) = make_ushort4(hh[0], hh[1], hh[2], hh[3]);
    *(ushort4*)(lo + i) = make_ushort4(ll[0], ll[1], ll[2], ll[3]);
}

// W1 [n][h][u] fp32 -> BT_hi/lo [n][u][h] bf16 (transposed, K=h contiguous)
__global__ void convert_B(const float* __restrict__ W1,
                          unsigned short* __restrict__ bhi,
                          unsigned short* __restrict__ blo) {
    __shared__ float t[64][65];
    int n = blockIdx.x, h0 = blockIdx.y * 64, u0 = blockIdx.z * 64;
    int tid = threadIdx.x;
    int ul = tid & 63;
    #pragma unroll
    for (int i = 0; i < 16; ++i) {
        int hl = i * 4 + (tid >> 6);
        t[hl][ul] = W1[((size_t)n * H_ + h0 + hl) * U_ + u0 + ul];
    }
    __syncthreads();
    #pragma unroll
    for (int i = 0; i < 16; ++i) {
        int ulw = i * 4 + (tid >> 6);
        int hlw = tid & 63;
        float f = t[hlw][ulw];
        unsigned short h = f2bf(f);
        float hf = __uint_as_float((unsigned)h << 16);
        size_t o = ((size_t)n * U_ + u0 + ulw) * H_ + h0 + hlw;
        bhi[o] = h;
        blo[o] = f2bf(f - hf);
    }
}

// qb[n,b,u] = sum_h query[b,h]*W2[n,h,u] + b1[n,u] + b2[n,u]   (exact fp32)
__global__ void qb_kernel(const float* __restrict__ query,
                          const float* __restrict__ W2,
                          const float* __restrict__ b1,
                          const float* __restrict__ b2,
                          float* __restrict__ qb) {
    int n = blockIdx.x >> 4;
    int b = blockIdx.x & 15;
    __shared__ float q[H_];
    int tid = threadIdx.x; // 0..511
    q[tid]       = query[b * H_ + tid];
    q[tid + 512] = query[b * H_ + tid + 512];
    __syncthreads();
    const float* w2 = W2 + (size_t)n * H_ * U_ + tid;
    float acc = 0.f;
    #pragma unroll 4
    for (int h = 0; h < H_; ++h) acc += q[h] * w2[(size_t)h * U_];
    acc += b1[n * U_ + tid] + b2[n * U_ + tid];
    qb[(n * B_ + b) * U_ + tid] = acc;
}

// ---------------- main: split-bf16 MFMA GEMM + tanh epilogue ----------------
// C = (Ahi+Alo)(Bhi+Blo) ~= AhiBhi + AhiBlo + AloBhi  (fp32 MFMA accum)
// 128x128 tile, BK=32, 4 waves (2x2), each wave 4x4 frags of 16x16x32.
__global__ __launch_bounds__(256, 2) void gemm_mfma(
        const unsigned short* __restrict__ Ahi, const unsigned short* __restrict__ Alo,
        const unsigned short* __restrict__ Bhi, const unsigned short* __restrict__ Blo,
        const float* __restrict__ qb, const float* __restrict__ Vw,
        const float* __restrict__ Ww, float* __restrict__ partial) {
    __shared__ unsigned short sAh[128 * 32], sAl[128 * 32];
    __shared__ unsigned short sBh[128 * 32], sBl[128 * 32];
    __shared__ float buf[128];

    int tid = threadIdx.x;
    int lane = tid & 63, wid = tid >> 6;
    int wr = wid >> 1, wc = wid & 1;
    int rowBase = blockIdx.x * 128;
    int colBase = blockIdx.y * 128;

    // each wave stages one 128x32 tile via global_load_lds (8 x 1KB instrs)
    const unsigned short* gsrc =
        (wid == 0) ? Ahi + (size_t)rowBase * H_ :
        (wid == 1) ? Alo + (size_t)rowBase * H_ :
        (wid == 2) ? Bhi + (size_t)colBase * H_ :
                     Blo + (size_t)colBase * H_;
    unsigned short* ldst = (wid == 0) ? sAh : (wid == 1) ? sAl
                         : (wid == 2) ? sBh : sBl;
    // per-lane src: row = lane>>2 (of 16 rows per instr), 16B chunk = lane&3
    const unsigned short* lanesrc = gsrc + (size_t)(lane >> 2) * H_ + (lane & 3) * 8;

    f32x4 acc[4][4];
    #pragma unroll
    for (int i = 0; i < 4; ++i)
        #pragma unroll
        for (int j = 0; j < 4; ++j) acc[i][j] = (f32x4){0.f, 0.f, 0.f, 0.f};

    // fragment ds_read byte offsets (row-major [128][64B]; rows alternate
    // bank halves at 64B stride -> conflict-free b128 floor, no swizzle)
    int offA = (wr * 64 + (lane & 15)) * 64 + (lane >> 4) * 16;
    int offB = (wc * 64 + (lane & 15)) * 64 + (lane >> 4) * 16;

    for (int k0 = 0; k0 < H_; k0 += 32) {
        const unsigned short* s = lanesrc + k0;
        #pragma unroll
        for (int g = 0; g < 8; ++g)
            gload_lds16(s + (size_t)g * 16 * H_, ldst + g * 512);
        __syncthreads();

        s16x8 ah[4], al[4], bh[4], bl[4];
        #pragma unroll
        for (int mi = 0; mi < 4; ++mi) {
            ah[mi] = *(const s16x8*)((const char*)sAh + offA + mi * 1024);
            al[mi] = *(const s16x8*)((const char*)sAl + offA + mi * 1024);
        }
        #pragma unroll
        for (int nn = 0; nn < 4; ++nn) {
            bh[nn] = *(const s16x8*)((const char*)sBh + offB + nn * 1024);
            bl[nn] = *(const s16x8*)((const char*)sBl + offB + nn * 1024);
        }
        #pragma unroll
        for (int mi = 0; mi < 4; ++mi)
            #pragma unroll
            for (int nn = 0; nn < 4; ++nn) {
                acc[mi][nn] = __builtin_amdgcn_mfma_f32_16x16x32_bf16(ah[mi], bh[nn], acc[mi][nn], 0, 0, 0);
                acc[mi][nn] = __builtin_amdgcn_mfma_f32_16x16x32_bf16(ah[mi], bl[nn], acc[mi][nn], 0, 0, 0);
                acc[mi][nn] = __builtin_amdgcn_mfma_f32_16x16x32_bf16(al[mi], bh[nn], acc[mi][nn], 0, 0, 0);
            }
        __syncthreads();
    }

    // epilogue: row partial = Ww[n] * sum_u Vw[u]*tanh(acc + qb[u])
    // D layout (m89): col = lane&15, row = (lane>>4)*4 + r
    int n = colBase >> 9;
    int b = rowBase >> 11;
    int u0 = (colBase & 511) + wc * 64;
    float wwn = Ww[n];
    float qv[4], vw[4];
    #pragma unroll
    for (int nn = 0; nn < 4; ++nn) {
        int u = u0 + nn * 16 + (lane & 15);
        qv[nn] = qb[((size_t)n * B_ + b) * U_ + u];
        vw[nn] = Vw[n * U_ + u];
    }
    float rs[16];
    #pragma unroll
    for (int mi = 0; mi < 4; ++mi)
        #pragma unroll
        for (int r = 0; r < 4; ++r) {
            float p = 0.f;
            #pragma unroll
            for (int nn = 0; nn < 4; ++nn)
                p += vw[nn] * fast_tanh(acc[mi][nn][r] + qv[nn]);
            p += __shfl_xor(p, 1);
            p += __shfl_xor(p, 2);
            p += __shfl_xor(p, 4);
            p += __shfl_xor(p, 8);
            rs[mi * 4 + r] = p;
        }
    if (wc == 1 && (lane & 15) == 0) {
        #pragma unroll
        for (int mi = 0; mi < 4; ++mi)
            #pragma unroll
            for (int r = 0; r < 4; ++r)
                buf[wr * 64 + mi * 16 + (lane >> 4) * 4 + r] = rs[mi * 4 + r];
    }
    __syncthreads();
    if (wc == 0 && (lane & 15) == 0) {
        #pragma unroll
        for (int mi = 0; mi < 4; ++mi)
            #pragma unroll
            for (int r = 0; r < 4; ++r) {
                int row = wr * 64 + mi * 16 + (lane >> 4) * 4 + r;
                partial[(size_t)blockIdx.y * M_ + rowBase + row] =
                    wwn * (rs[mi * 4 + r] + buf[row]);
            }
    }
}

// ---------------- fallback fp32 GEMM (if ws too small) ----------------
__global__ __launch_bounds__(256, 2) void gemm_score(
        const float* __restrict__ values,
        const float* __restrict__ W1,
        const float* __restrict__ qb,
        const float* __restrict__ Vw,
        const float* __restrict__ Ww,
        float* __restrict__ partial) {
    __shared__ float As[16][128 + 4];
    __shared__ float Bs[16][128 + 4];
    int tid = threadIdx.x;
    int tx = tid & 15, ty = tid >> 4;
    int rowBase = blockIdx.x * 128;
    int colBase = blockIdx.y * 128;
    int n = colBase >> 9;
    int u0 = colBase & 511;
    int b = rowBase >> 11;
    float acc[8][8];
    #pragma unroll
    for (int i = 0; i < 8; ++i)
        #pragma unroll
        for (int j = 0; j < 8; ++j) acc[i][j] = 0.f;
    const float* Ag = values + (size_t)rowBase * H_;
    const float* Bg = W1 + (size_t)n * H_ * U_ + u0;
    for (int k0 = 0; k0 < H_; k0 += 16) {
        #pragma unroll
        for (int r = 0; r < 2; ++r) {
            int idx = tid + r * 256;
            int arow = idx >> 2, aqc = idx & 3;
            float4 v = *(const float4*)(Ag + (size_t)arow * H_ + k0 + aqc * 4);
            As[aqc * 4 + 0][arow] = v.x;
            As[aqc * 4 + 1][arow] = v.y;
            As[aqc * 4 + 2][arow] = v.z;
            As[aqc * 4 + 3][arow] = v.w;
        }
        #pragma unroll
        for (int r = 0; r < 2; ++r) {
            int idx = tid + r * 256;
            int bk = idx >> 5, bqc = idx & 31;
            float4 v = *(const float4*)(Bg + (size_t)(k0 + bk) * U_ + bqc * 4);
            *(float4*)&Bs[bk][bqc * 4] = v;
        }
        __syncthreads();
        #pragma unroll
        for (int k = 0; k < 16; ++k) {
            float4 a0 = *(const float4*)&As[k][ty * 8];
            float4 a1 = *(const float4*)&As[k][ty * 8 + 4];
            float4 b0 = *(const float4*)&Bs[k][tx * 8];
            float4 b1v = *(const float4*)&Bs[k][tx * 8 + 4];
            float av[8] = {a0.x, a0.y, a0.z, a0.w, a1.x, a1.y, a1.z, a1.w};
            float bv[8] = {b0.x, b0.y, b0.z, b0.w, b1v.x, b1v.y, b1v.z, b1v.w};
            #pragma unroll
            for (int i = 0; i < 8; ++i)
                #pragma unroll
                for (int j = 0; j < 8; ++j)
                    acc[i][j] = fmaf(av[i], bv[j], acc[i][j]);
        }
        __syncthreads();
    }
    float qbv[8], vwv[8];
    #pragma unroll
    for (int j = 0; j < 8; ++j) {
        int u = u0 + tx * 8 + j;
        qbv[j] = qb[(n * B_ + b) * U_ + u];
        vwv[j] = Vw[n * U_ + u];
    }
    float wwn = Ww[n];
    #pragma unroll
    for (int i = 0; i < 8; ++i) {
        float p = 0.f;
        #pragma unroll
        for (int j = 0; j < 8; ++j)
            p += vwv[j] * fast_tanh(acc[i][j] + qbv[j]);
        p += __shfl_xor(p, 1);
        p += __shfl_xor(p, 2);
        p += __shfl_xor(p, 4);
        p += __shfl_xor(p, 8);
        if (tx == 0)
            partial[(size_t)blockIdx.y * M_ + rowBase + ty * 8 + i] = wwn * p;
    }
}

// ---------------- tail kernels ----------------
__global__ void reduce_score(const float* __restrict__ partial,
                             float* __restrict__ score) {
    int row = blockIdx.x * blockDim.x + threadIdx.x;
    float s = 0.f;
    #pragma unroll
    for (int ct = 0; ct < NCOLT; ++ct) s += partial[(size_t)ct * M_ + row];
    score[row] = s;
}

__global__ __launch_bounds__(1024) void topk_kernel(
        const float* __restrict__ score,
        const float* __restrict__ Vb,
        const float* __restrict__ Ww,
        const float* __restrict__ Wb,
        float* __restrict__ out_masked,
        float* __restrict__ w_un) {
    __shared__ float sc[S_];
    __shared__ float srt[S_];
    __shared__ int cnt_gt;
    int b = blockIdx.x;
    int tid = threadIdx.x;
    float cst = Wb[0];
    #pragma unroll
    for (int n2 = 0; n2 < NH; ++n2) cst += Ww[n2] * Vb[n2];
    for (int s = tid; s < S_; s += 1024) {
        float v = score[b * S_ + s] + cst;
        sc[s] = v; srt[s] = v;
    }
    if (tid == 0) cnt_gt = 0;
    __syncthreads();
    for (int k = 2; k <= S_; k <<= 1) {
        for (int j = k >> 1; j >= 1; j >>= 1) {
            int i = ((tid & ~(j - 1)) << 1) | (tid & (j - 1));
            int p = i | j;
            float a = srt[i], c2 = srt[p];
            if (((i & k) == 0) ? (a > c2) : (a < c2)) { srt[i] = c2; srt[p] = a; }
            __syncthreads();
        }
    }
    float T = srt[S_ - TOPK];
    int c = 0;
    for (int s = tid; s < S_; s += 1024) c += (sc[s] > T);
    atomicAdd(&cnt_gt, c);
    __syncthreads();
    int need_eq = TOPK - cnt_gt;
    for (int s = tid; s < S_; s += 1024) {
        float v = sc[s];
        bool sel = (v > T);
        if (v == T) {
            int rank = 0;
            for (int t2 = 0; t2 < s; ++t2) rank += (sc[t2] == T);
            sel = (rank < need_eq);
        }
        float m = sel ? v : 0.f;
        out_masked[b * S_ + s] = m;
        w_un[b * S_ + s] = 1.f / (1.f + __expf(-m));
    }
}

__global__ void norm_w(const float* __restrict__ w_un, float* __restrict__ out_w) {
    int s = blockIdx.x * blockDim.x + threadIdx.x;
    float d = 0.f;
    #pragma unroll
    for (int b = 0; b < B_; ++b) d += w_un[b * S_ + s];
    float inv = 1.f / d;
    #pragma unroll
    for (int b = 0; b < B_; ++b) out_w[b * S_ + s] = w_un[b * S_ + s] * inv;
}

__global__ void ctx_partial(const float* __restrict__ values,
                            const float* __restrict__ w,
                            float* __restrict__ pctx) {
    int bb = blockIdx.x;
    int h = blockIdx.y * 256 + threadIdx.x;
    int s0 = blockIdx.z * 256;
    __shared__ float wrow[256];
    wrow[threadIdx.x] = w[bb * S_ + s0 + threadIdx.x];
    __syncthreads();
    const float* vp = values + (size_t)(bb * S_ + s0) * H_ + h;
    float acc = 0.f;
    #pragma unroll 4
    for (int s = 0; s < 256; ++s) acc += wrow[s] * vp[(size_t)s * H_];
    pctx[((size_t)blockIdx.z * B_ + bb) * H_ + h] = acc;
}

__global__ void ctx_reduce(const float* __restrict__ pctx,
                           float* __restrict__ out_ctx) {
    int i = blockIdx.x * blockDim.x + threadIdx.x;
    float s = 0.f;
    #pragma unroll
    for (int z = 0; z < 8; ++z) s += pctx[(size_t)z * B_ * H_ + i];
    out_ctx[i] = s;
}

extern "C" void kernel_launch(void* const* d_in, const int* in_sizes, int n_in,
                              void* d_out, int out_size, void* d_ws, size_t ws_size,
                              hipStream_t stream) {
    const float* query = (const float*)d_in[0];
    const float* values = (const float*)d_in[1];
    const float* W1 = (const float*)d_in[2];
    const float* b1 = (const float*)d_in[3];
    const float* W2 = (const float*)d_in[4];
    const float* b2 = (const float*)d_in[5];
    const float* Vw = (const float*)d_in[6];
    const float* Vb = (const float*)d_in[7];
    const float* Ww = (const float*)d_in[8];
    const float* Wb = (const float*)d_in[9];

    float* ws = (float*)d_ws;
    float* qb      = ws;                     // 65536
    float* partial = qb + 65536;             // 32*32768 = 1048576
    float* score   = partial + 1048576;      // 32768
    float* w_un    = score + 32768;          // 32768
    float* pctx    = w_un + 32768;           // 131072
    unsigned short* Ahi = (unsigned short*)(pctx + 131072); // 33554432
    unsigned short* Alo = Ahi + (size_t)M_ * H_;            // 33554432
    unsigned short* Bhi = Alo + (size_t)M_ * H_;            // 4194304
    unsigned short* Blo = Bhi + (size_t)NC * H_;            // 4194304
    size_t needed = (size_t)((char*)(Blo + (size_t)NC * H_) - (char*)d_ws);

    float* out_ctx    = (float*)d_out;       // 16384
    float* out_w      = out_ctx + 16384;     // 32768
    float* out_masked = out_w + 32768;       // 32768

    qb_kernel<<<dim3(NH * B_), 512, 0, stream>>>(query, W2, b1, b2, qb);
    if (ws_size >= needed) {
        convert_A<<<dim3(32768), 256, 0, stream>>>(values, Ahi, Alo);
        convert_B<<<dim3(NH, 16, 8), 256, 0, stream>>>(W1, Bhi, Blo);
        gemm_mfma<<<dim3(256, 32), 256, 0, stream>>>(Ahi, Alo, Bhi, Blo,
                                                     qb, Vw, Ww, partial);
    } else {
        gemm_score<<<dim3(256, 32), 256, 0, stream>>>(values, W1, qb, Vw, Ww, partial);
    }
    reduce_score<<<128, 256, 0, stream>>>(partial, score);
    topk_kernel<<<16, 1024, 0, stream>>>(score, Vb, Ww, Wb, out_masked, w_un);
    norm_w<<<8, 256, 0, stream>>>(w_un, out_w);
    ctx_partial<<<dim3(16, 4, 8), 256, 0, stream>>>(values, out_w, pctx);
    ctx_reduce<<<64, 256, 0, stream>>>(pctx, out_ctx);
}

// Round 3
// 1094.087 us; speedup vs baseline: 2.9159x; 1.0613x over previous
//
#include <hip/hip_runtime.h>
#include <hip/hip_bf16.h>

#define B_ 16
#define S_ 2048
#define H_ 1024
#define U_ 512
#define NH 8
#define TOPK 100

#define M_ (B_*S_)      // 32768 rows (b,s)
#define NC (NH*U_)      // 4096 cols (n,u)

typedef short s16x8 __attribute__((ext_vector_type(8)));
typedef float f32x4 __attribute__((ext_vector_type(4)));

__device__ __forceinline__ float fast_tanh(float x) {
    float e = __expf(2.f * x);
    return (e - 1.f) / (e + 1.f);
}

__device__ __forceinline__ unsigned short f2bf(float f) {
    unsigned u = __float_as_uint(f);
    u = u + 0x7fffu + ((u >> 16) & 1u);
    return (unsigned short)(u >> 16);
}

__device__ __forceinline__ void gl16(const unsigned short* g, unsigned short* l) {
    __builtin_amdgcn_global_load_lds(
        (const __attribute__((address_space(1))) void*)g,
        (__attribute__((address_space(3))) void*)l, 16, 0, 0);
}

// ---------------- prep: fp32 -> bf16 hi/lo ----------------
__global__ void convert_A(const float* __restrict__ v,
                          unsigned short* __restrict__ hi,
                          unsigned short* __restrict__ lo) {
    size_t i = ((size_t)blockIdx.x * 256 + threadIdx.x) * 4;
    float4 f = *(const float4*)(v + i);
    float c[4] = {f.x, f.y, f.z, f.w};
    unsigned short hh[4], ll[4];
    #pragma unroll
    for (int j = 0; j < 4; ++j) {
        unsigned short h = f2bf(c[j]);
        float hf = __uint_as_float((unsigned)h << 16);
        hh[j] = h;
        ll[j] = f2bf(c[j] - hf);
    }
    *(ushort4*)(hi + i) = make_ushort4(hh[0], hh[1], hh[2], hh[3]);
    *(ushort4*)(lo + i) = make_ushort4(ll[0], ll[1], ll[2], ll[3]);
}

// W1 [n][h][u] fp32 -> BT_hi/lo [n][u][h] bf16 (transposed, K contiguous)
__global__ void convert_B(const float* __restrict__ W1,
                          unsigned short* __restrict__ bhi,
                          unsigned short* __restrict__ blo) {
    __shared__ float t[64][65];
    int n = blockIdx.x, h0 = blockIdx.y * 64, u0 = blockIdx.z * 64;
    int tid = threadIdx.x;
    int ul = tid & 63;
    #pragma unroll
    for (int i = 0; i < 16; ++i) {
        int hl = i * 4 + (tid >> 6);
        t[hl][ul] = W1[((size_t)n * H_ + h0 + hl) * U_ + u0 + ul];
    }
    __syncthreads();
    #pragma unroll
    for (int i = 0; i < 16; ++i) {
        int ulw = i * 4 + (tid >> 6);
        int hlw = tid & 63;
        float f = t[hlw][ulw];
        unsigned short h = f2bf(f);
        float hf = __uint_as_float((unsigned)h << 16);
        size_t o = ((size_t)n * U_ + u0 + ulw) * H_ + h0 + hlw;
        bhi[o] = h;
        blo[o] = f2bf(f - hf);
    }
}

// qb[n,b,u] = sum_h query[b,h]*W2[n,h,u] + b1[n,u] + b2[n,u]   (exact fp32)
__global__ void qb_kernel(const float* __restrict__ query,
                          const float* __restrict__ W2,
                          const float* __restrict__ b1,
                          const float* __restrict__ b2,
                          float* __restrict__ qb) {
    int n = blockIdx.x >> 4;
    int b = blockIdx.x & 15;
    __shared__ float q[H_];
    int tid = threadIdx.x;
    q[tid]       = query[b * H_ + tid];
    q[tid + 512] = query[b * H_ + tid + 512];
    __syncthreads();
    const float* w2 = W2 + (size_t)n * H_ * U_ + tid;
    float acc = 0.f;
    #pragma unroll 4
    for (int h = 0; h < H_; ++h) acc += q[h] * w2[(size_t)h * U_];
    acc += b1[n * U_ + tid] + b2[n * U_ + tid];
    qb[(n * B_ + b) * U_ + tid] = acc;
}

// ---------------- main: 8-phase-style counted-vmcnt split-bf16 GEMM ----------------
// Virtual K'=3072: seg0 Ahi*Bhi, seg1 Ahi*Blo, seg2 Alo*Bhi (32 K-tiles of 32 each).
// BM=BN=256, 8 waves (2x4), 4-slot LDS ring (32KB/K-tile), vmcnt(8) boundary waits.
#define NT 96
#define SWZ(d) ((d) ^ ((((d) >> 7) & 3) << 4))
#define ASRC(tt) (((tt) < 64) ? Ahi : Alo)
#define BSRC(tt) ((((tt) >> 5) == 1) ? Blo : Bhi)
#define K0(tt) (((tt) & 31) * 32)
#define STAGE_A(tt, j) gl16(ASRC(tt) + (size_t)(rowBase + (j)*128 + rT) * 1024 + K0(tt) + cT, \
                            (unsigned short*)lds + ((tt)&3)*16384 + (j)*4096 + tid*8)
#define STAGE_B(tt, j) gl16(BSRC(tt) + (size_t)(colBase + (j)*128 + rT) * 1024 + K0(tt) + cT, \
                            (unsigned short*)lds + ((tt)&3)*16384 + 8192 + (j)*4096 + tid*8)

__global__ __launch_bounds__(512, 1) void gemm8(
        const unsigned short* __restrict__ Ahi, const unsigned short* __restrict__ Alo,
        const unsigned short* __restrict__ Bhi, const unsigned short* __restrict__ Blo,
        const float* __restrict__ qb, const float* __restrict__ Vw,
        const float* __restrict__ Ww, float* __restrict__ partial) {
    __shared__ unsigned short lds[65536];   // 128 KB: 4 slots x (A 16KB | B 16KB)
    const int tid = threadIdx.x;
    const int lane = tid & 63;
    const int wid = tid >> 6;
    const int wm = wid >> 2, wn = wid & 3;   // 2 x 4 wave grid
    int bid = blockIdx.x;
    int swz = (bid & 7) * 256 + (bid >> 3);  // XCD swizzle (2048 % 8 == 0)
    int mIdx = swz & 127, nIdx = swz >> 7;
    int rowBase = mIdx * 256, colBase = nIdx * 256;

    // staging source decode (constant per thread): linear LDS dst -> swizzled global src
    int d0 = tid * 16;
    int d0s = SWZ(d0);
    int rT = d0s >> 6;          // row 0..127 within 128-row chunk
    int cT = (d0s & 63) >> 1;   // elem col (multiple of 8)

    // fragment ds_read byte offsets (region-relative, swizzled)
    const int l15 = lane & 15, l4 = lane >> 4;
    int offA[8], offB[4];
    #pragma unroll
    for (int m = 0; m < 8; ++m) {
        int d = (wm * 128 + m * 16 + l15) * 64 + l4 * 16;
        offA[m] = SWZ(d);
    }
    #pragma unroll
    for (int n = 0; n < 4; ++n) {
        int d = (wn * 64 + n * 16 + l15) * 64 + l4 * 16;
        offB[n] = 16384 + SWZ(d);
    }

    f32x4 acc[8][4];
    #pragma unroll
    for (int m = 0; m < 8; ++m)
        #pragma unroll
        for (int n = 0; n < 4; ++n) acc[m][n] = (f32x4){0.f, 0.f, 0.f, 0.f};

    // prologue: stage tiles 0..2 (12 loads/wave)
    #pragma unroll
    for (int tt = 0; tt < 3; ++tt) {
        STAGE_A(tt, 0); STAGE_A(tt, 1);
        STAGE_B(tt, 0); STAGE_B(tt, 1);
    }
    asm volatile("s_waitcnt vmcnt(8)" ::: "memory");   // tile 0 resident
    __builtin_amdgcn_s_barrier();

    #pragma unroll 1
    for (int t = 0; t < NT; ++t) {
        const char* slot = (const char*)lds + (t & 3) * 32768;
        s16x8 bf[4], af[4];
        // ---- phase 0: B frags + A m0-3, stage A of t+3, MFMA quadrant 0 ----
        #pragma unroll
        for (int n = 0; n < 4; ++n) bf[n] = *(const s16x8*)(slot + offB[n]);
        #pragma unroll
        for (int m = 0; m < 4; ++m) af[m] = *(const s16x8*)(slot + offA[m]);
        if (t <= NT - 4) { STAGE_A(t + 3, 0); STAGE_A(t + 3, 1); }
        __builtin_amdgcn_s_barrier();
        asm volatile("s_waitcnt lgkmcnt(0)" ::: "memory");
        __builtin_amdgcn_s_setprio(1);
        #pragma unroll
        for (int m = 0; m < 4; ++m)
            #pragma unroll
            for (int n = 0; n < 4; ++n)
                acc[m][n] = __builtin_amdgcn_mfma_f32_16x16x32_bf16(af[m], bf[n], acc[m][n], 0, 0, 0);
        __builtin_amdgcn_s_setprio(0);
        __builtin_amdgcn_s_barrier();
        // ---- phase 1: A m4-7, stage B of t+3, MFMA quadrant 1, boundary vmcnt ----
        #pragma unroll
        for (int m = 0; m < 4; ++m) af[m] = *(const s16x8*)(slot + offA[4 + m]);
        if (t <= NT - 4) { STAGE_B(t + 3, 0); STAGE_B(t + 3, 1); }
        __builtin_amdgcn_s_barrier();
        asm volatile("s_waitcnt lgkmcnt(0)" ::: "memory");
        __builtin_amdgcn_s_setprio(1);
        #pragma unroll
        for (int m = 0; m < 4; ++m)
            #pragma unroll
            for (int n = 0; n < 4; ++n)
                acc[4 + m][n] = __builtin_amdgcn_mfma_f32_16x16x32_bf16(af[m], bf[n], acc[4 + m][n], 0, 0, 0);
        __builtin_amdgcn_s_setprio(0);
        if (t < NT - 3)       asm volatile("s_waitcnt vmcnt(8)" ::: "memory");
        else if (t == NT - 3) asm volatile("s_waitcnt vmcnt(4)" ::: "memory");
        else if (t == NT - 2) asm volatile("s_waitcnt vmcnt(0)" ::: "memory");
        __builtin_amdgcn_s_barrier();
    }

    // epilogue: tanh + Vw*Ww row-reduce, cross-wave LDS reduce
    __syncthreads();
    int hd = colBase >> 9;
    int b = rowBase >> 11;
    float wwn = Ww[hd];
    float qv[4], vw[4];
    #pragma unroll
    for (int n = 0; n < 4; ++n) {
        int u = (colBase & 511) + wn * 64 + n * 16 + l15;
        qv[n] = qb[((size_t)hd * B_ + b) * U_ + u];
        vw[n] = Vw[hd * U_ + u] * wwn;
    }
    float* red = (float*)lds;   // [4 wn][256 rows]
    #pragma unroll
    for (int m = 0; m < 8; ++m)
        #pragma unroll
        for (int r = 0; r < 4; ++r) {
            float p = 0.f;
            #pragma unroll
            for (int n = 0; n < 4; ++n)
                p += vw[n] * fast_tanh(acc[m][n][r] + qv[n]);
            p += __shfl_xor(p, 1);
            p += __shfl_xor(p, 2);
            p += __shfl_xor(p, 4);
            p += __shfl_xor(p, 8);
            if (l15 == 0)
                red[wn * 256 + wm * 128 + m * 16 + l4 * 4 + r] = p;
        }
    __syncthreads();
    if (tid < 256) {
        float s = red[tid] + red[256 + tid] + red[512 + tid] + red[768 + tid];
        partial[(size_t)nIdx * M_ + rowBase + tid] = s;
    }
}

// ---------------- fallback fp32 GEMM (if ws too small) ----------------
__global__ __launch_bounds__(256, 2) void gemm_score(
        const float* __restrict__ values,
        const float* __restrict__ W1,
        const float* __restrict__ qb,
        const float* __restrict__ Vw,
        const float* __restrict__ Ww,
        float* __restrict__ partial) {
    __shared__ float As[16][128 + 4];
    __shared__ float Bs[16][128 + 4];
    int tid = threadIdx.x;
    int tx = tid & 15, ty = tid >> 4;
    int rowBase = blockIdx.x * 128;
    int colBase = blockIdx.y * 128;
    int n = colBase >> 9;
    int u0 = colBase & 511;
    int b = rowBase >> 11;
    float acc[8][8];
    #pragma unroll
    for (int i = 0; i < 8; ++i)
        #pragma unroll
        for (int j = 0; j < 8; ++j) acc[i][j] = 0.f;
    const float* Ag = values + (size_t)rowBase * H_;
    const float* Bg = W1 + (size_t)n * H_ * U_ + u0;
    for (int k0 = 0; k0 < H_; k0 += 16) {
        #pragma unroll
        for (int r = 0; r < 2; ++r) {
            int idx = tid + r * 256;
            int arow = idx >> 2, aqc = idx & 3;
            float4 v = *(const float4*)(Ag + (size_t)arow * H_ + k0 + aqc * 4);
            As[aqc * 4 + 0][arow] = v.x;
            As[aqc * 4 + 1][arow] = v.y;
            As[aqc * 4 + 2][arow] = v.z;
            As[aqc * 4 + 3][arow] = v.w;
        }
        #pragma unroll
        for (int r = 0; r < 2; ++r) {
            int idx = tid + r * 256;
            int bk = idx >> 5, bqc = idx & 31;
            float4 v = *(const float4*)(Bg + (size_t)(k0 + bk) * U_ + bqc * 4);
            *(float4*)&Bs[bk][bqc * 4] = v;
        }
        __syncthreads();
        #pragma unroll
        for (int k = 0; k < 16; ++k) {
            float4 a0 = *(const float4*)&As[k][ty * 8];
            float4 a1 = *(const float4*)&As[k][ty * 8 + 4];
            float4 b0 = *(const float4*)&Bs[k][tx * 8];
            float4 b1v = *(const float4*)&Bs[k][tx * 8 + 4];
            float av[8] = {a0.x, a0.y, a0.z, a0.w, a1.x, a1.y, a1.z, a1.w};
            float bv[8] = {b0.x, b0.y, b0.z, b0.w, b1v.x, b1v.y, b1v.z, b1v.w};
            #pragma unroll
            for (int i = 0; i < 8; ++i)
                #pragma unroll
                for (int j = 0; j < 8; ++j)
                    acc[i][j] = fmaf(av[i], bv[j], acc[i][j]);
        }
        __syncthreads();
    }
    float qbv[8], vwv[8];
    #pragma unroll
    for (int j = 0; j < 8; ++j) {
        int u = u0 + tx * 8 + j;
        qbv[j] = qb[(n * B_ + b) * U_ + u];
        vwv[j] = Vw[n * U_ + u];
    }
    float wwn = Ww[n];
    #pragma unroll
    for (int i = 0; i < 8; ++i) {
        float p = 0.f;
        #pragma unroll
        for (int j = 0; j < 8; ++j)
            p += vwv[j] * fast_tanh(acc[i][j] + qbv[j]);
        p += __shfl_xor(p, 1);
        p += __shfl_xor(p, 2);
        p += __shfl_xor(p, 4);
        p += __shfl_xor(p, 8);
        if (tx == 0)
            partial[(size_t)blockIdx.y * M_ + rowBase + ty * 8 + i] = wwn * p;
    }
}

// ---------------- tail kernels ----------------
__global__ void reduce_score(const float* __restrict__ partial,
                             float* __restrict__ score, int nparts) {
    int row = blockIdx.x * blockDim.x + threadIdx.x;
    float s = 0.f;
    for (int ct = 0; ct < nparts; ++ct) s += partial[(size_t)ct * M_ + row];
    score[row] = s;
}

__global__ __launch_bounds__(1024) void topk_kernel(
        const float* __restrict__ score,
        const float* __restrict__ Vb,
        const float* __restrict__ Ww,
        const float* __restrict__ Wb,
        float* __restrict__ out_masked,
        float* __restrict__ w_un) {
    __shared__ float sc[S_];
    __shared__ float srt[S_];
    __shared__ int cnt_gt;
    int b = blockIdx.x;
    int tid = threadIdx.x;
    float cst = Wb[0];
    #pragma unroll
    for (int n2 = 0; n2 < NH; ++n2) cst += Ww[n2] * Vb[n2];
    for (int s = tid; s < S_; s += 1024) {
        float v = score[b * S_ + s] + cst;
        sc[s] = v; srt[s] = v;
    }
    if (tid == 0) cnt_gt = 0;
    __syncthreads();
    for (int k = 2; k <= S_; k <<= 1) {
        for (int j = k >> 1; j >= 1; j >>= 1) {
            int i = ((tid & ~(j - 1)) << 1) | (tid & (j - 1));
            int p = i | j;
            float a = srt[i], c2 = srt[p];
            if (((i & k) == 0) ? (a > c2) : (a < c2)) { srt[i] = c2; srt[p] = a; }
            __syncthreads();
        }
    }
    float T = srt[S_ - TOPK];
    int c = 0;
    for (int s = tid; s < S_; s += 1024) c += (sc[s] > T);
    atomicAdd(&cnt_gt, c);
    __syncthreads();
    int need_eq = TOPK - cnt_gt;
    for (int s = tid; s < S_; s += 1024) {
        float v = sc[s];
        bool sel = (v > T);
        if (v == T) {
            int rank = 0;
            for (int t2 = 0; t2 < s; ++t2) rank += (sc[t2] == T);
            sel = (rank < need_eq);
        }
        float m = sel ? v : 0.f;
        out_masked[b * S_ + s] = m;
        w_un[b * S_ + s] = 1.f / (1.f + __expf(-m));
    }
}

__global__ void norm_w(const float* __restrict__ w_un, float* __restrict__ out_w) {
    int s = blockIdx.x * blockDim.x + threadIdx.x;
    float d = 0.f;
    #pragma unroll
    for (int b = 0; b < B_; ++b) d += w_un[b * S_ + s];
    float inv = 1.f / d;
    #pragma unroll
    for (int b = 0; b < B_; ++b) out_w[b * S_ + s] = w_un[b * S_ + s] * inv;
}

__global__ void ctx_partial(const float* __restrict__ values,
                            const float* __restrict__ w,
                            float* __restrict__ pctx) {
    int bb = blockIdx.x;
    int h = blockIdx.y * 256 + threadIdx.x;
    int s0 = blockIdx.z * 256;
    __shared__ float wrow[256];
    wrow[threadIdx.x] = w[bb * S_ + s0 + threadIdx.x];
    __syncthreads();
    const float* vp = values + (size_t)(bb * S_ + s0) * H_ + h;
    float acc = 0.f;
    #pragma unroll 4
    for (int s = 0; s < 256; ++s) acc += wrow[s] * vp[(size_t)s * H_];
    pctx[((size_t)blockIdx.z * B_ + bb) * H_ + h] = acc;
}

__global__ void ctx_reduce(const float* __restrict__ pctx,
                           float* __restrict__ out_ctx) {
    int i = blockIdx.x * blockDim.x + threadIdx.x;
    float s = 0.f;
    #pragma unroll
    for (int z = 0; z < 8; ++z) s += pctx[(size_t)z * B_ * H_ + i];
    out_ctx[i] = s;
}

extern "C" void kernel_launch(void* const* d_in, const int* in_sizes, int n_in,
                              void* d_out, int out_size, void* d_ws, size_t ws_size,
                              hipStream_t stream) {
    const float* query = (const float*)d_in[0];
    const float* values = (const float*)d_in[1];
    const float* W1 = (const float*)d_in[2];
    const float* b1 = (const float*)d_in[3];
    const float* W2 = (const float*)d_in[4];
    const float* b2 = (const float*)d_in[5];
    const float* Vw = (const float*)d_in[6];
    const float* Vb = (const float*)d_in[7];
    const float* Ww = (const float*)d_in[8];
    const float* Wb = (const float*)d_in[9];

    float* ws = (float*)d_ws;
    float* qb      = ws;                     // 65536
    float* partial = qb + 65536;             // 32*32768
    float* score   = partial + 1048576;      // 32768
    float* w_un    = score + 32768;          // 32768
    float* pctx    = w_un + 32768;           // 131072
    unsigned short* Ahi = (unsigned short*)(pctx + 131072);
    unsigned short* Alo = Ahi + (size_t)M_ * H_;
    unsigned short* Bhi = Alo + (size_t)M_ * H_;
    unsigned short* Blo = Bhi + (size_t)NC * H_;
    size_t needed = (size_t)((char*)(Blo + (size_t)NC * H_) - (char*)d_ws);

    float* out_ctx    = (float*)d_out;       // 16384
    float* out_w      = out_ctx + 16384;     // 32768
    float* out_masked = out_w + 32768;       // 32768

    qb_kernel<<<dim3(NH * B_), 512, 0, stream>>>(query, W2, b1, b2, qb);
    if (ws_size >= needed) {
        convert_A<<<dim3(32768), 256, 0, stream>>>(values, Ahi, Alo);
        convert_B<<<dim3(NH, 16, 8), 256, 0, stream>>>(W1, Bhi, Blo);
        gemm8<<<dim3(2048), 512, 0, stream>>>(Ahi, Alo, Bhi, Blo, qb, Vw, Ww, partial);
        reduce_score<<<128, 256, 0, stream>>>(partial, score, 16);
    } else {
        gemm_score<<<dim3(256, 32), 256, 0, stream>>>(values, W1, qb, Vw, Ww, partial);
        reduce_score<<<128, 256, 0, stream>>>(partial, score, 32);
    }
    topk_kernel<<<16, 1024, 0, stream>>>(score, Vb, Ww, Wb, out_masked, w_un);
    norm_w<<<8, 256, 0, stream>>>(w_un, out_w);
    ctx_partial<<<dim3(16, 4, 8), 256, 0, stream>>>(values, out_w, pctx);
    ctx_reduce<<<64, 256, 0, stream>>>(pctx, out_ctx);
}